// Round 1
// baseline (434.907 us; speedup 1.0000x reference)
//
#include <hip/hip_runtime.h>

#define N_NODES 50000
#define E_EDGES 800000
#define NE_TOT  (E_EDGES + N_NODES)   // edges + self loops = 850000
#define IND     128
#define HID     64
#define CAP     64                    // max in-degree bucket (Poisson(17): P(>=64) ~ 1e-19)
#define NEG_SLOPE 0.2f

// ---------------------------------------------------------------- utilities
__global__ void k_zero(int* __restrict__ cnt, float* __restrict__ sums) {
    int i = blockIdx.x * 256 + threadIdx.x;
    if (i < N_NODES) cnt[i] = 0;
    if (i < 128) sums[i] = 0.f;
}

// ---------------------------------------------------------------- GEMM1: h1 = x @ W1, + alpha dots
__global__ __launch_bounds__(256) void k_gemm1(
    const float* __restrict__ x, const float* __restrict__ W1,
    const float* __restrict__ as_w, const float* __restrict__ ad_w,
    float* __restrict__ h, float* __restrict__ as_out, float* __restrict__ ad_out)
{
    __shared__ float sW[IND * HID];   // 32 KB
    __shared__ float sAs[HID], sAd[HID];
    int tid = threadIdx.x;
    for (int i = tid; i < IND * HID / 4; i += 256)
        ((float4*)sW)[i] = ((const float4*)W1)[i];
    if (tid < HID) { sAs[tid] = as_w[tid]; sAd[tid] = ad_w[tid]; }
    __syncthreads();

    int wave = tid >> 6, lane = tid & 63;
    int rowBase = blockIdx.x * 16 + wave * 4;
    for (int r = 0; r < 4; ++r) {
        int row = rowBase + r;
        if (row >= N_NODES) return;
        const float4* xr = (const float4*)(x + (size_t)row * IND);
        float acc = 0.f;
#pragma unroll
        for (int k4 = 0; k4 < IND / 4; ++k4) {
            float4 xv = xr[k4];
            acc = fmaf(xv.x, sW[(k4 * 4 + 0) * HID + lane], acc);
            acc = fmaf(xv.y, sW[(k4 * 4 + 1) * HID + lane], acc);
            acc = fmaf(xv.z, sW[(k4 * 4 + 2) * HID + lane], acc);
            acc = fmaf(xv.w, sW[(k4 * 4 + 3) * HID + lane], acc);
        }
        h[(size_t)row * HID + lane] = acc;
        float vs = acc * sAs[lane];
        float vd = acc * sAd[lane];
        for (int off = 32; off; off >>= 1) {
            vs += __shfl_xor(vs, off, 64);
            vd += __shfl_xor(vd, off, 64);
        }
        if (lane == 0) { as_out[row] = vs; ad_out[row] = vd; }
    }
}

// ---------------------------------------------------------------- edge scatter into per-dst buckets
__global__ void k_scatter(const int* __restrict__ ei, int* __restrict__ cnt, int* __restrict__ bucket) {
    int i = blockIdx.x * 256 + threadIdx.x;
    if (i >= NE_TOT) return;
    int s, d;
    if (i < E_EDGES) { s = ei[i]; d = ei[E_EDGES + i]; }
    else { s = i - E_EDGES; d = s; }           // self loop
    int pos = atomicAdd(&cnt[d], 1);
    if (pos < CAP) bucket[(size_t)d * CAP + pos] = s;
}

// ---------------------------------------------------------------- per-dst softmax-weighted aggregation
__global__ __launch_bounds__(256) void k_agg(
    const float* __restrict__ hin, const float* __restrict__ as_, const float* __restrict__ ad_,
    const int* __restrict__ cnt, const int* __restrict__ bucket,
    const float* __restrict__ bias, float* __restrict__ out)
{
    int wave = threadIdx.x >> 6, lane = threadIdx.x & 63;
    int n = blockIdx.x * 4 + wave;
    if (n >= N_NODES) return;
    int deg = min(cnt[n], CAP);
    const int* bk = bucket + (size_t)n * CAP;
    float adn = ad_[n];

    float m = -1e30f;
    for (int t = 0; t < deg; ++t) {
        float e = as_[bk[t]] + adn;
        e = e > 0.f ? e : NEG_SLOPE * e;
        m = fmaxf(m, e);
    }
    float denom = 0.f, acc = 0.f;
    for (int t = 0; t < deg; ++t) {
        int s = bk[t];
        float e = as_[s] + adn;
        e = e > 0.f ? e : NEG_SLOPE * e;
        float w = __expf(e - m);
        denom += w;
        acc = fmaf(w, hin[(size_t)s * HID + lane], acc);
    }
    float inv = 1.f / (denom + 1e-16f);
    out[(size_t)n * HID + lane] = acc * inv + bias[lane];
}

// ---------------------------------------------------------------- BN statistics (two-stage)
__global__ __launch_bounds__(256) void k_bnstats(const float* __restrict__ h, float* __restrict__ sums) {
    int lane = threadIdx.x & 63, wave = threadIdx.x >> 6;
    float s = 0.f, ss = 0.f;
    for (int r = blockIdx.x * 4 + wave; r < N_NODES; r += gridDim.x * 4) {
        float v = h[(size_t)r * HID + lane];
        s += v; ss = fmaf(v, v, ss);
    }
    __shared__ float ls[4][64], lss[4][64];
    ls[wave][lane] = s; lss[wave][lane] = ss;
    __syncthreads();
    if (wave == 0) {
        s  = ls[0][lane] + ls[1][lane] + ls[2][lane] + ls[3][lane];
        ss = lss[0][lane] + lss[1][lane] + lss[2][lane] + lss[3][lane];
        atomicAdd(&sums[lane], s);
        atomicAdd(&sums[64 + lane], ss);
    }
}

__global__ void k_bnfinal(const float* __restrict__ sums, const float* __restrict__ gamma,
                          const float* __restrict__ beta, float* __restrict__ ss_out) {
    int j = threadIdx.x;
    if (j >= 64) return;
    float mean = sums[j] * (1.f / N_NODES);
    float var  = sums[64 + j] * (1.f / N_NODES) - mean * mean;
    float sc = gamma[j] * rsqrtf(var + 1e-5f);
    ss_out[j] = sc;
    ss_out[64 + j] = beta[j] - mean * sc;
}

// ---------------------------------------------------------------- GEMM2 with fused BN+ReLU input
__global__ __launch_bounds__(256) void k_gemm2(
    const float* __restrict__ hin, const float* __restrict__ W2, const float* __restrict__ ss,
    const float* __restrict__ as_w, const float* __restrict__ ad_w,
    float* __restrict__ h2, float* __restrict__ as_out, float* __restrict__ ad_out)
{
    __shared__ float sW[64 * 64];     // 16 KB
    __shared__ float sScale[64], sShift[64], sAs[64], sAd[64];
    int tid = threadIdx.x;
    for (int i = tid; i < 64 * 64 / 4; i += 256)
        ((float4*)sW)[i] = ((const float4*)W2)[i];
    if (tid < 64) {
        sScale[tid] = ss[tid]; sShift[tid] = ss[64 + tid];
        sAs[tid] = as_w[tid];  sAd[tid] = ad_w[tid];
    }
    __syncthreads();

    int wave = tid >> 6, lane = tid & 63;
    int rowBase = blockIdx.x * 16 + wave * 4;
    for (int r = 0; r < 4; ++r) {
        int row = rowBase + r;
        if (row >= N_NODES) return;
        const float4* xr = (const float4*)(hin + (size_t)row * 64);
        float acc = 0.f;
#pragma unroll
        for (int k4 = 0; k4 < 16; ++k4) {
            float4 xv = xr[k4];
            float a0 = fmaxf(fmaf(xv.x, sScale[4 * k4 + 0], sShift[4 * k4 + 0]), 0.f);
            float a1 = fmaxf(fmaf(xv.y, sScale[4 * k4 + 1], sShift[4 * k4 + 1]), 0.f);
            float a2 = fmaxf(fmaf(xv.z, sScale[4 * k4 + 2], sShift[4 * k4 + 2]), 0.f);
            float a3 = fmaxf(fmaf(xv.w, sScale[4 * k4 + 3], sShift[4 * k4 + 3]), 0.f);
            acc = fmaf(a0, sW[(4 * k4 + 0) * 64 + lane], acc);
            acc = fmaf(a1, sW[(4 * k4 + 1) * 64 + lane], acc);
            acc = fmaf(a2, sW[(4 * k4 + 2) * 64 + lane], acc);
            acc = fmaf(a3, sW[(4 * k4 + 3) * 64 + lane], acc);
        }
        h2[(size_t)row * 64 + lane] = acc;
        float vs = acc * sAs[lane];
        float vd = acc * sAd[lane];
        for (int off = 32; off; off >>= 1) {
            vs += __shfl_xor(vs, off, 64);
            vd += __shfl_xor(vd, off, 64);
        }
        if (lane == 0) { as_out[row] = vs; ad_out[row] = vd; }
    }
}

// ---------------------------------------------------------------- launch
extern "C" void kernel_launch(void* const* d_in, const int* in_sizes, int n_in,
                              void* d_out, int out_size, void* d_ws, size_t ws_size,
                              hipStream_t stream) {
    const float* x        = (const float*)d_in[0];
    const int*   ei       = (const int*)d_in[1];
    const float* W1       = (const float*)d_in[2];
    const float* att_src1 = (const float*)d_in[3];
    const float* att_dst1 = (const float*)d_in[4];
    const float* bias1    = (const float*)d_in[5];
    const float* gamma    = (const float*)d_in[6];
    const float* beta     = (const float*)d_in[7];
    const float* W2       = (const float*)d_in[8];
    const float* att_src2 = (const float*)d_in[9];
    const float* att_dst2 = (const float*)d_in[10];
    const float* bias2    = (const float*)d_in[11];
    float* out = (float*)d_out;

    // workspace layout (256B aligned)
    char* ws = (char*)d_ws;
    size_t off = 0;
    auto alloc = [&](size_t bytes) { void* p = ws + off; off = (off + bytes + 255) & ~(size_t)255; return p; };
    float* h1     = (float*)alloc((size_t)N_NODES * HID * 4);
    float* as1    = (float*)alloc((size_t)N_NODES * 4);
    float* ad1    = (float*)alloc((size_t)N_NODES * 4);
    float* h1agg  = (float*)alloc((size_t)N_NODES * HID * 4);
    float* h2     = (float*)alloc((size_t)N_NODES * HID * 4);
    float* as2    = (float*)alloc((size_t)N_NODES * 4);
    float* ad2    = (float*)alloc((size_t)N_NODES * 4);
    int*   cnt    = (int*)alloc((size_t)N_NODES * 4);
    int*   bucket = (int*)alloc((size_t)N_NODES * CAP * 4);
    float* sums   = (float*)alloc(128 * 4);
    float* bn_ss  = (float*)alloc(128 * 4);

    k_zero<<<(N_NODES + 255) / 256, 256, 0, stream>>>(cnt, sums);
    k_gemm1<<<(N_NODES + 15) / 16, 256, 0, stream>>>(x, W1, att_src1, att_dst1, h1, as1, ad1);
    k_scatter<<<(NE_TOT + 255) / 256, 256, 0, stream>>>(ei, cnt, bucket);
    k_agg<<<(N_NODES + 3) / 4, 256, 0, stream>>>(h1, as1, ad1, cnt, bucket, bias1, h1agg);
    k_bnstats<<<256, 256, 0, stream>>>(h1agg, sums);
    k_bnfinal<<<1, 64, 0, stream>>>(sums, gamma, beta, bn_ss);
    k_gemm2<<<(N_NODES + 15) / 16, 256, 0, stream>>>(h1agg, W2, bn_ss, att_src2, att_dst2, h2, as2, ad2);
    k_agg<<<(N_NODES + 3) / 4, 256, 0, stream>>>(h2, as2, ad2, cnt, bucket, bias2, out);
}

// Round 2
// 241.505 us; speedup vs baseline: 1.8008x; 1.8008x over previous
//
#include <hip/hip_runtime.h>

#define N_NODES 50000
#define E_EDGES 800000
#define NE_TOT  (E_EDGES + N_NODES)   // edges + self loops = 850000
#define IND     128
#define HID     64
#define CAP     64                    // max in-degree bucket (Poisson(17): P(>=64) ~ 1e-19)
#define NEG_SLOPE 0.2f

// ---------------------------------------------------------------- utilities
__global__ void k_zero(int* __restrict__ cnt, float* __restrict__ sums) {
    int i = blockIdx.x * 256 + threadIdx.x;
    if (i < N_NODES) cnt[i] = 0;
    if (i < 128) sums[i] = 0.f;
}

// ---------------------------------------------------------------- GEMM1: h1 = x @ W1, + alpha dots
// 4 rows per wave share each LDS W-column read (4x fewer ds_read than 1:1).
__global__ __launch_bounds__(256) void k_gemm1(
    const float* __restrict__ x, const float* __restrict__ W1,
    const float* __restrict__ as_w, const float* __restrict__ ad_w,
    float* __restrict__ h, float* __restrict__ as_out, float* __restrict__ ad_out)
{
    __shared__ float sW[IND * HID];   // 32 KB
    __shared__ float sAs[HID], sAd[HID];
    int tid = threadIdx.x;
    for (int i = tid; i < IND * HID / 4; i += 256)
        ((float4*)sW)[i] = ((const float4*)W1)[i];
    if (tid < HID) { sAs[tid] = as_w[tid]; sAd[tid] = ad_w[tid]; }
    __syncthreads();

    int wave = tid >> 6, lane = tid & 63;
    int row0 = blockIdx.x * 16 + wave * 4;        // 50000 = 16*3125, no tail
    const float4* xr0 = (const float4*)(x + (size_t)(row0 + 0) * IND);
    const float4* xr1 = (const float4*)(x + (size_t)(row0 + 1) * IND);
    const float4* xr2 = (const float4*)(x + (size_t)(row0 + 2) * IND);
    const float4* xr3 = (const float4*)(x + (size_t)(row0 + 3) * IND);
    float acc0 = 0.f, acc1 = 0.f, acc2 = 0.f, acc3 = 0.f;
#pragma unroll 8
    for (int k4 = 0; k4 < IND / 4; ++k4) {
        float4 x0 = xr0[k4], x1 = xr1[k4], x2 = xr2[k4], x3 = xr3[k4];
        float xa0[4] = {x0.x, x0.y, x0.z, x0.w};
        float xa1[4] = {x1.x, x1.y, x1.z, x1.w};
        float xa2[4] = {x2.x, x2.y, x2.z, x2.w};
        float xa3[4] = {x3.x, x3.y, x3.z, x3.w};
#pragma unroll
        for (int j = 0; j < 4; ++j) {
            float w = sW[(k4 * 4 + j) * HID + lane];
            acc0 = fmaf(xa0[j], w, acc0);
            acc1 = fmaf(xa1[j], w, acc1);
            acc2 = fmaf(xa2[j], w, acc2);
            acc3 = fmaf(xa3[j], w, acc3);
        }
    }
    float accs[4] = {acc0, acc1, acc2, acc3};
#pragma unroll
    for (int r = 0; r < 4; ++r) {
        int row = row0 + r;
        float acc = accs[r];
        h[(size_t)row * HID + lane] = acc;
        float vs = acc * sAs[lane];
        float vd = acc * sAd[lane];
        for (int off = 32; off; off >>= 1) {
            vs += __shfl_xor(vs, off, 64);
            vd += __shfl_xor(vd, off, 64);
        }
        if (lane == 0) { as_out[row] = vs; ad_out[row] = vd; }
    }
}

// ---------------------------------------------------------------- edge scatter into per-dst buckets
__global__ void k_scatter(const int* __restrict__ ei, int* __restrict__ cnt, int* __restrict__ bucket) {
    int i = blockIdx.x * 256 + threadIdx.x;
    if (i >= NE_TOT) return;
    int s, d;
    if (i < E_EDGES) { s = ei[i]; d = ei[E_EDGES + i]; }
    else { s = i - E_EDGES; d = s; }           // self loop
    int pos = atomicAdd(&cnt[d], 1);
    if (pos < CAP) bucket[(size_t)d * CAP + pos] = s;
}

// ---------------------------------------------------------------- per-dst softmax-weighted aggregation
// Lane-parallel weights (one gather for all edges of the node), shfl-broadcast
// accumulate with 8 independent gathers in flight per iteration.
__global__ __launch_bounds__(256) void k_agg(
    const float* __restrict__ hin, const float* __restrict__ as_, const float* __restrict__ ad_,
    const int* __restrict__ cnt, const int* __restrict__ bucket,
    const float* __restrict__ bias, float* __restrict__ out)
{
    int wave = threadIdx.x >> 6, lane = threadIdx.x & 63;
    int n = blockIdx.x * 4 + wave;
    if (n >= N_NODES) return;
    int deg = min(cnt[n], CAP);
    const int* bk = bucket + (size_t)n * CAP;
    float adn = ad_[n];

    // lane-parallel edge weight computation (each lane owns one edge)
    int s_l = 0;
    float e = -1e30f;
    if (lane < deg) {
        s_l = bk[lane];
        float t = as_[s_l] + adn;
        e = t > 0.f ? t : NEG_SLOPE * t;
    }
    float m = e;
    for (int off = 32; off; off >>= 1) m = fmaxf(m, __shfl_xor(m, off, 64));
    float w_l = (lane < deg) ? __expf(e - m) : 0.f;
    float denom = w_l;
    for (int off = 32; off; off >>= 1) denom += __shfl_xor(denom, off, 64);

    // accumulate: 8 edges per iteration -> 8 independent 256B gathers in flight
    float acc = 0.f;
    for (int t = 0; t < deg; t += 8) {
        int s0 = __shfl(s_l, t + 0), s1 = __shfl(s_l, t + 1);
        int s2 = __shfl(s_l, t + 2), s3 = __shfl(s_l, t + 3);
        int s4 = __shfl(s_l, t + 4), s5 = __shfl(s_l, t + 5);
        int s6 = __shfl(s_l, t + 6), s7 = __shfl(s_l, t + 7);
        float w0 = __shfl(w_l, t + 0), w1 = __shfl(w_l, t + 1);
        float w2 = __shfl(w_l, t + 2), w3 = __shfl(w_l, t + 3);
        float w4 = __shfl(w_l, t + 4), w5 = __shfl(w_l, t + 5);
        float w6 = __shfl(w_l, t + 6), w7 = __shfl(w_l, t + 7);
        float v0 = hin[(size_t)s0 * HID + lane];
        float v1 = hin[(size_t)s1 * HID + lane];
        float v2 = hin[(size_t)s2 * HID + lane];
        float v3 = hin[(size_t)s3 * HID + lane];
        float v4 = hin[(size_t)s4 * HID + lane];
        float v5 = hin[(size_t)s5 * HID + lane];
        float v6 = hin[(size_t)s6 * HID + lane];
        float v7 = hin[(size_t)s7 * HID + lane];
        acc = fmaf(w0, v0, acc); acc = fmaf(w1, v1, acc);
        acc = fmaf(w2, v2, acc); acc = fmaf(w3, v3, acc);
        acc = fmaf(w4, v4, acc); acc = fmaf(w5, v5, acc);
        acc = fmaf(w6, v6, acc); acc = fmaf(w7, v7, acc);
    }
    float inv = 1.f / (denom + 1e-16f);
    out[(size_t)n * HID + lane] = acc * inv + bias[lane];
}

// ---------------------------------------------------------------- BN statistics (two-stage)
__global__ __launch_bounds__(256) void k_bnstats(const float* __restrict__ h, float* __restrict__ sums) {
    int lane = threadIdx.x & 63, wave = threadIdx.x >> 6;
    float s = 0.f, ss = 0.f;
    for (int r = blockIdx.x * 4 + wave; r < N_NODES; r += gridDim.x * 4) {
        float v = h[(size_t)r * HID + lane];
        s += v; ss = fmaf(v, v, ss);
    }
    __shared__ float ls[4][64], lss[4][64];
    ls[wave][lane] = s; lss[wave][lane] = ss;
    __syncthreads();
    if (wave == 0) {
        s  = ls[0][lane] + ls[1][lane] + ls[2][lane] + ls[3][lane];
        ss = lss[0][lane] + lss[1][lane] + lss[2][lane] + lss[3][lane];
        atomicAdd(&sums[lane], s);
        atomicAdd(&sums[64 + lane], ss);
    }
}

__global__ void k_bnfinal(const float* __restrict__ sums, const float* __restrict__ gamma,
                          const float* __restrict__ beta, float* __restrict__ ss_out) {
    int j = threadIdx.x;
    if (j >= 64) return;
    float mean = sums[j] * (1.f / N_NODES);
    float var  = sums[64 + j] * (1.f / N_NODES) - mean * mean;
    float sc = gamma[j] * rsqrtf(var + 1e-5f);
    ss_out[j] = sc;
    ss_out[64 + j] = beta[j] - mean * sc;
}

// ---------------------------------------------------------------- GEMM2 with fused BN+ReLU input
__global__ __launch_bounds__(256) void k_gemm2(
    const float* __restrict__ hin, const float* __restrict__ W2, const float* __restrict__ ss,
    const float* __restrict__ as_w, const float* __restrict__ ad_w,
    float* __restrict__ h2, float* __restrict__ as_out, float* __restrict__ ad_out)
{
    __shared__ float sW[64 * 64];     // 16 KB
    __shared__ float sScale[64], sShift[64], sAs[64], sAd[64];
    int tid = threadIdx.x;
    for (int i = tid; i < 64 * 64 / 4; i += 256)
        ((float4*)sW)[i] = ((const float4*)W2)[i];
    if (tid < 64) {
        sScale[tid] = ss[tid]; sShift[tid] = ss[64 + tid];
        sAs[tid] = as_w[tid];  sAd[tid] = ad_w[tid];
    }
    __syncthreads();

    int wave = tid >> 6, lane = tid & 63;
    int row0 = blockIdx.x * 16 + wave * 4;        // 50000 = 16*3125, no tail
    const float4* xr0 = (const float4*)(hin + (size_t)(row0 + 0) * 64);
    const float4* xr1 = (const float4*)(hin + (size_t)(row0 + 1) * 64);
    const float4* xr2 = (const float4*)(hin + (size_t)(row0 + 2) * 64);
    const float4* xr3 = (const float4*)(hin + (size_t)(row0 + 3) * 64);
    float acc0 = 0.f, acc1 = 0.f, acc2 = 0.f, acc3 = 0.f;
#pragma unroll 4
    for (int k4 = 0; k4 < 16; ++k4) {
        float4 x0 = xr0[k4], x1 = xr1[k4], x2 = xr2[k4], x3 = xr3[k4];
        float xa0[4] = {x0.x, x0.y, x0.z, x0.w};
        float xa1[4] = {x1.x, x1.y, x1.z, x1.w};
        float xa2[4] = {x2.x, x2.y, x2.z, x2.w};
        float xa3[4] = {x3.x, x3.y, x3.z, x3.w};
#pragma unroll
        for (int j = 0; j < 4; ++j) {
            int k = k4 * 4 + j;
            float sc = sScale[k], sh = sShift[k];
            float a0 = fmaxf(fmaf(xa0[j], sc, sh), 0.f);
            float a1 = fmaxf(fmaf(xa1[j], sc, sh), 0.f);
            float a2 = fmaxf(fmaf(xa2[j], sc, sh), 0.f);
            float a3 = fmaxf(fmaf(xa3[j], sc, sh), 0.f);
            float w = sW[k * 64 + lane];
            acc0 = fmaf(a0, w, acc0);
            acc1 = fmaf(a1, w, acc1);
            acc2 = fmaf(a2, w, acc2);
            acc3 = fmaf(a3, w, acc3);
        }
    }
    float accs[4] = {acc0, acc1, acc2, acc3};
#pragma unroll
    for (int r = 0; r < 4; ++r) {
        int row = row0 + r;
        float acc = accs[r];
        h2[(size_t)row * 64 + lane] = acc;
        float vs = acc * sAs[lane];
        float vd = acc * sAd[lane];
        for (int off = 32; off; off >>= 1) {
            vs += __shfl_xor(vs, off, 64);
            vd += __shfl_xor(vd, off, 64);
        }
        if (lane == 0) { as_out[row] = vs; ad_out[row] = vd; }
    }
}

// ---------------------------------------------------------------- launch
extern "C" void kernel_launch(void* const* d_in, const int* in_sizes, int n_in,
                              void* d_out, int out_size, void* d_ws, size_t ws_size,
                              hipStream_t stream) {
    const float* x        = (const float*)d_in[0];
    const int*   ei       = (const int*)d_in[1];
    const float* W1       = (const float*)d_in[2];
    const float* att_src1 = (const float*)d_in[3];
    const float* att_dst1 = (const float*)d_in[4];
    const float* bias1    = (const float*)d_in[5];
    const float* gamma    = (const float*)d_in[6];
    const float* beta     = (const float*)d_in[7];
    const float* W2       = (const float*)d_in[8];
    const float* att_src2 = (const float*)d_in[9];
    const float* att_dst2 = (const float*)d_in[10];
    const float* bias2    = (const float*)d_in[11];
    float* out = (float*)d_out;

    // workspace layout (256B aligned)
    char* ws = (char*)d_ws;
    size_t off = 0;
    auto alloc = [&](size_t bytes) { void* p = ws + off; off = (off + bytes + 255) & ~(size_t)255; return p; };
    float* h1     = (float*)alloc((size_t)N_NODES * HID * 4);
    float* as1    = (float*)alloc((size_t)N_NODES * 4);
    float* ad1    = (float*)alloc((size_t)N_NODES * 4);
    float* h1agg  = (float*)alloc((size_t)N_NODES * HID * 4);
    float* h2     = (float*)alloc((size_t)N_NODES * HID * 4);
    float* as2    = (float*)alloc((size_t)N_NODES * 4);
    float* ad2    = (float*)alloc((size_t)N_NODES * 4);
    int*   cnt    = (int*)alloc((size_t)N_NODES * 4);
    int*   bucket = (int*)alloc((size_t)N_NODES * CAP * 4);
    float* sums   = (float*)alloc(128 * 4);
    float* bn_ss  = (float*)alloc(128 * 4);

    k_zero<<<(N_NODES + 255) / 256, 256, 0, stream>>>(cnt, sums);
    k_gemm1<<<3125, 256, 0, stream>>>(x, W1, att_src1, att_dst1, h1, as1, ad1);
    k_scatter<<<(NE_TOT + 255) / 256, 256, 0, stream>>>(ei, cnt, bucket);
    k_agg<<<(N_NODES + 3) / 4, 256, 0, stream>>>(h1, as1, ad1, cnt, bucket, bias1, h1agg);
    k_bnstats<<<256, 256, 0, stream>>>(h1agg, sums);
    k_bnfinal<<<1, 64, 0, stream>>>(sums, gamma, beta, bn_ss);
    k_gemm2<<<3125, 256, 0, stream>>>(h1agg, W2, bn_ss, att_src2, att_dst2, h2, as2, ad2);
    k_agg<<<(N_NODES + 3) / 4, 256, 0, stream>>>(h2, as2, ad2, cnt, bucket, bias2, out);
}

// Round 3
// 197.259 us; speedup vs baseline: 2.2047x; 1.2243x over previous
//
#include <hip/hip_runtime.h>

#define N_NODES 50000
#define E_EDGES 800000
#define NE_TOT  (E_EDGES + N_NODES)   // edges + self loops = 850000
#define IND     128
#define HID     64
#define CAP     64                    // max in-degree (Poisson(17): P(>=64) ~ 1e-19)
#define NEG_SLOPE 0.2f

// ---------------------------------------------------------------- utilities
__global__ void k_zero(int* __restrict__ cnt, float* __restrict__ sums) {
    int i = blockIdx.x * 256 + threadIdx.x;
    if (i < N_NODES) cnt[i] = 0;
    if (i < 128) sums[i] = 0.f;
}

// ---------------------------------------------------------------- GEMM1: h1 = x @ W1 (+ alpha dots)
// x tile staged in LDS (coalesced); 8 rows/wave; W-column read shared by 8 accs.
__global__ __launch_bounds__(256) void k_gemm1(
    const float* __restrict__ x, const float* __restrict__ W1,
    const float* __restrict__ as_w, const float* __restrict__ ad_w,
    float* __restrict__ h, float* __restrict__ as_out, float* __restrict__ ad_out)
{
    __shared__ float sW[IND * HID];     // 32 KB  [k][64]
    __shared__ float sX[32][IND];       // 16 KB  [row][k]
    __shared__ float sAs[HID], sAd[HID];
    int tid = threadIdx.x;
    int row0 = blockIdx.x * 32;

    for (int i = tid; i < IND * HID / 4; i += 256)
        ((float4*)sW)[i] = ((const float4*)W1)[i];
#pragma unroll
    for (int i = 0; i < 4; ++i) {                 // 1024 float4 of x-tile
        int idx = tid + i * 256;
        int r = idx >> 5, c4 = idx & 31;          // 32 float4 per row
        int gr = row0 + r; if (gr >= N_NODES) gr = N_NODES - 1;
        ((float4*)&sX[r][0])[c4] = ((const float4*)(x + (size_t)gr * IND))[c4];
    }
    if (tid < HID) { sAs[tid] = as_w[tid]; sAd[tid] = ad_w[tid]; }
    __syncthreads();

    int wave = tid >> 6, lane = tid & 63;
    int rloc = wave * 8;
    float acc[8] = {0.f, 0.f, 0.f, 0.f, 0.f, 0.f, 0.f, 0.f};
#pragma unroll 4
    for (int k4 = 0; k4 < IND / 4; ++k4) {
        float w0 = sW[(k4 * 4 + 0) * HID + lane];
        float w1 = sW[(k4 * 4 + 1) * HID + lane];
        float w2 = sW[(k4 * 4 + 2) * HID + lane];
        float w3 = sW[(k4 * 4 + 3) * HID + lane];
#pragma unroll
        for (int r = 0; r < 8; ++r) {
            float4 xv = *(const float4*)&sX[rloc + r][k4 * 4];   // uniform broadcast
            acc[r] = fmaf(xv.x, w0, acc[r]);
            acc[r] = fmaf(xv.y, w1, acc[r]);
            acc[r] = fmaf(xv.z, w2, acc[r]);
            acc[r] = fmaf(xv.w, w3, acc[r]);
        }
    }
#pragma unroll
    for (int r = 0; r < 8; ++r) {
        int row = row0 + rloc + r;
        if (row >= N_NODES) break;
        float a = acc[r];
        h[(size_t)row * HID + lane] = a;
        float vs = a * sAs[lane];
        float vd = a * sAd[lane];
        for (int off = 32; off; off >>= 1) {
            vs += __shfl_xor(vs, off, 64);
            vd += __shfl_xor(vd, off, 64);
        }
        if (lane == 0) { as_out[row] = vs; ad_out[row] = vd; }
    }
}

// ---------------------------------------------------------------- edge scatter, transposed u16 buckets
// bucket[slot*N + dst] : hot region ~ deg_avg * 100KB, 32 stores per 64B line.
__global__ void k_scatter(const int* __restrict__ ei, int* __restrict__ cnt,
                          unsigned short* __restrict__ bucket) {
    int i = blockIdx.x * 256 + threadIdx.x;
    if (i >= NE_TOT) return;
    int s, d;
    if (i < E_EDGES) { s = ei[i]; d = ei[E_EDGES + i]; }
    else { s = i - E_EDGES; d = s; }           // self loop
    int pos = atomicAdd(&cnt[d], 1);
    if (pos < CAP) bucket[(size_t)pos * N_NODES + d] = (unsigned short)s;
}

// ---------------------------------------------------------------- per-dst softmax aggregation
__global__ __launch_bounds__(256) void k_agg(
    const float* __restrict__ hin, const float* __restrict__ as_, const float* __restrict__ ad_,
    const int* __restrict__ cnt, const unsigned short* __restrict__ bucket,
    const float* __restrict__ bias, float* __restrict__ out)
{
    int wave = threadIdx.x >> 6, lane = threadIdx.x & 63;
    int n = blockIdx.x * 4 + wave;
    if (n >= N_NODES) return;
    int deg = min(cnt[n], CAP);
    float adn = ad_[n];

    // lane-parallel: lane t owns edge slot t
    int s_l = 0;
    float e = -1e30f;
    if (lane < deg) {
        s_l = (int)bucket[(size_t)lane * N_NODES + n];
        float t = as_[s_l] + adn;
        e = t > 0.f ? t : NEG_SLOPE * t;
    }
    float m = e;
    for (int off = 32; off; off >>= 1) m = fmaxf(m, __shfl_xor(m, off, 64));
    float w_l = (lane < deg) ? __expf(e - m) : 0.f;
    float denom = w_l;
    for (int off = 32; off; off >>= 1) denom += __shfl_xor(denom, off, 64);

    // accumulate: 8 independent 256B gathers in flight
    float acc = 0.f;
    for (int t = 0; t < deg; t += 8) {
        int s0 = __shfl(s_l, t + 0), s1 = __shfl(s_l, t + 1);
        int s2 = __shfl(s_l, t + 2), s3 = __shfl(s_l, t + 3);
        int s4 = __shfl(s_l, t + 4), s5 = __shfl(s_l, t + 5);
        int s6 = __shfl(s_l, t + 6), s7 = __shfl(s_l, t + 7);
        float w0 = __shfl(w_l, t + 0), w1 = __shfl(w_l, t + 1);
        float w2 = __shfl(w_l, t + 2), w3 = __shfl(w_l, t + 3);
        float w4 = __shfl(w_l, t + 4), w5 = __shfl(w_l, t + 5);
        float w6 = __shfl(w_l, t + 6), w7 = __shfl(w_l, t + 7);
        float v0 = hin[(size_t)s0 * HID + lane];
        float v1 = hin[(size_t)s1 * HID + lane];
        float v2 = hin[(size_t)s2 * HID + lane];
        float v3 = hin[(size_t)s3 * HID + lane];
        float v4 = hin[(size_t)s4 * HID + lane];
        float v5 = hin[(size_t)s5 * HID + lane];
        float v6 = hin[(size_t)s6 * HID + lane];
        float v7 = hin[(size_t)s7 * HID + lane];
        acc = fmaf(w0, v0, acc); acc = fmaf(w1, v1, acc);
        acc = fmaf(w2, v2, acc); acc = fmaf(w3, v3, acc);
        acc = fmaf(w4, v4, acc); acc = fmaf(w5, v5, acc);
        acc = fmaf(w6, v6, acc); acc = fmaf(w7, v7, acc);
    }
    float inv = 1.f / (denom + 1e-16f);
    out[(size_t)n * HID + lane] = acc * inv + bias[lane];
}

// ---------------------------------------------------------------- BN statistics (two-stage)
__global__ __launch_bounds__(256) void k_bnstats(const float* __restrict__ h, float* __restrict__ sums) {
    int lane = threadIdx.x & 63, wave = threadIdx.x >> 6;
    float s = 0.f, ss = 0.f;
    for (int r = blockIdx.x * 4 + wave; r < N_NODES; r += gridDim.x * 4) {
        float v = h[(size_t)r * HID + lane];
        s += v; ss = fmaf(v, v, ss);
    }
    __shared__ float ls[4][64], lss[4][64];
    ls[wave][lane] = s; lss[wave][lane] = ss;
    __syncthreads();
    if (wave == 0) {
        s  = ls[0][lane] + ls[1][lane] + ls[2][lane] + ls[3][lane];
        ss = lss[0][lane] + lss[1][lane] + lss[2][lane] + lss[3][lane];
        atomicAdd(&sums[lane], s);
        atomicAdd(&sums[64 + lane], ss);
    }
}

__global__ void k_bnfinal(const float* __restrict__ sums, const float* __restrict__ gamma,
                          const float* __restrict__ beta, float* __restrict__ ss_out) {
    int j = threadIdx.x;
    if (j >= 64) return;
    float mean = sums[j] * (1.f / N_NODES);
    float var  = sums[64 + j] * (1.f / N_NODES) - mean * mean;
    float sc = gamma[j] * rsqrtf(var + 1e-5f);
    ss_out[j] = sc;
    ss_out[64 + j] = beta[j] - mean * sc;
}

// ---------------------------------------------------------------- GEMM2, BN+ReLU fused into staging
__global__ __launch_bounds__(256) void k_gemm2(
    const float* __restrict__ hin, const float* __restrict__ W2, const float* __restrict__ ss,
    const float* __restrict__ as_w, const float* __restrict__ ad_w,
    float* __restrict__ h2, float* __restrict__ as_out, float* __restrict__ ad_out)
{
    __shared__ float sW[HID * HID];     // 16 KB
    __shared__ float sX[32][HID];       // 8 KB (BN+ReLU applied)
    __shared__ float sAs[HID], sAd[HID];
    int tid = threadIdx.x;
    int row0 = blockIdx.x * 32;

    for (int i = tid; i < HID * HID / 4; i += 256)
        ((float4*)sW)[i] = ((const float4*)W2)[i];
#pragma unroll
    for (int i = 0; i < 2; ++i) {                 // 512 float4 of tile
        int idx = tid + i * 256;
        int r = idx >> 4, c4 = idx & 15;          // 16 float4 per row
        int gr = row0 + r; if (gr >= N_NODES) gr = N_NODES - 1;
        float4 xv = ((const float4*)(hin + (size_t)gr * HID))[c4];
        float4 sc = ((const float4*)ss)[c4];
        float4 sh = ((const float4*)(ss + HID))[c4];
        float4 a;
        a.x = fmaxf(fmaf(xv.x, sc.x, sh.x), 0.f);
        a.y = fmaxf(fmaf(xv.y, sc.y, sh.y), 0.f);
        a.z = fmaxf(fmaf(xv.z, sc.z, sh.z), 0.f);
        a.w = fmaxf(fmaf(xv.w, sc.w, sh.w), 0.f);
        ((float4*)&sX[r][0])[c4] = a;
    }
    if (tid < HID) { sAs[tid] = as_w[tid]; sAd[tid] = ad_w[tid]; }
    __syncthreads();

    int wave = tid >> 6, lane = tid & 63;
    int rloc = wave * 8;
    float acc[8] = {0.f, 0.f, 0.f, 0.f, 0.f, 0.f, 0.f, 0.f};
#pragma unroll 4
    for (int k4 = 0; k4 < HID / 4; ++k4) {
        float w0 = sW[(k4 * 4 + 0) * HID + lane];
        float w1 = sW[(k4 * 4 + 1) * HID + lane];
        float w2 = sW[(k4 * 4 + 2) * HID + lane];
        float w3 = sW[(k4 * 4 + 3) * HID + lane];
#pragma unroll
        for (int r = 0; r < 8; ++r) {
            float4 xv = *(const float4*)&sX[rloc + r][k4 * 4];
            acc[r] = fmaf(xv.x, w0, acc[r]);
            acc[r] = fmaf(xv.y, w1, acc[r]);
            acc[r] = fmaf(xv.z, w2, acc[r]);
            acc[r] = fmaf(xv.w, w3, acc[r]);
        }
    }
#pragma unroll
    for (int r = 0; r < 8; ++r) {
        int row = row0 + rloc + r;
        if (row >= N_NODES) break;
        float a = acc[r];
        h2[(size_t)row * HID + lane] = a;
        float vs = a * sAs[lane];
        float vd = a * sAd[lane];
        for (int off = 32; off; off >>= 1) {
            vs += __shfl_xor(vs, off, 64);
            vd += __shfl_xor(vd, off, 64);
        }
        if (lane == 0) { as_out[row] = vs; ad_out[row] = vd; }
    }
}

// ---------------------------------------------------------------- launch
extern "C" void kernel_launch(void* const* d_in, const int* in_sizes, int n_in,
                              void* d_out, int out_size, void* d_ws, size_t ws_size,
                              hipStream_t stream) {
    const float* x        = (const float*)d_in[0];
    const int*   ei       = (const int*)d_in[1];
    const float* W1       = (const float*)d_in[2];
    const float* att_src1 = (const float*)d_in[3];
    const float* att_dst1 = (const float*)d_in[4];
    const float* bias1    = (const float*)d_in[5];
    const float* gamma    = (const float*)d_in[6];
    const float* beta     = (const float*)d_in[7];
    const float* W2       = (const float*)d_in[8];
    const float* att_src2 = (const float*)d_in[9];
    const float* att_dst2 = (const float*)d_in[10];
    const float* bias2    = (const float*)d_in[11];
    float* out = (float*)d_out;

    // workspace layout (256B aligned)
    char* ws = (char*)d_ws;
    size_t off = 0;
    auto alloc = [&](size_t bytes) { void* p = ws + off; off = (off + bytes + 255) & ~(size_t)255; return p; };
    float* h1     = (float*)alloc((size_t)N_NODES * HID * 4);
    float* as1    = (float*)alloc((size_t)N_NODES * 4);
    float* ad1    = (float*)alloc((size_t)N_NODES * 4);
    float* h1agg  = (float*)alloc((size_t)N_NODES * HID * 4);
    float* h2     = (float*)alloc((size_t)N_NODES * HID * 4);
    float* as2    = (float*)alloc((size_t)N_NODES * 4);
    float* ad2    = (float*)alloc((size_t)N_NODES * 4);
    int*   cnt    = (int*)alloc((size_t)N_NODES * 4);
    unsigned short* bucket = (unsigned short*)alloc((size_t)CAP * N_NODES * 2);
    float* sums   = (float*)alloc(128 * 4);
    float* bn_ss  = (float*)alloc(128 * 4);

    int gemmBlocks = (N_NODES + 31) / 32;   // 1563
    k_zero<<<(N_NODES + 255) / 256, 256, 0, stream>>>(cnt, sums);
    k_gemm1<<<gemmBlocks, 256, 0, stream>>>(x, W1, att_src1, att_dst1, h1, as1, ad1);
    k_scatter<<<(NE_TOT + 255) / 256, 256, 0, stream>>>(ei, cnt, bucket);
    k_agg<<<(N_NODES + 3) / 4, 256, 0, stream>>>(h1, as1, ad1, cnt, bucket, bias1, h1agg);
    k_bnstats<<<256, 256, 0, stream>>>(h1agg, sums);
    k_bnfinal<<<1, 64, 0, stream>>>(sums, gamma, beta, bn_ss);
    k_gemm2<<<gemmBlocks, 256, 0, stream>>>(h1agg, W2, bn_ss, att_src2, att_dst2, h2, as2, ad2);
    k_agg<<<(N_NODES + 3) / 4, 256, 0, stream>>>(h2, as2, ad2, cnt, bucket, bias2, out);
}

// Round 5
// 164.668 us; speedup vs baseline: 2.6411x; 1.1979x over previous
//
#include <hip/hip_runtime.h>

#define N_NODES 50000
#define E_EDGES 800000
#define NE_TOT  (E_EDGES + N_NODES)   // edges + self loops = 850000
#define IND     128
#define HID     64
#define CAP     64                    // max in-degree (Poisson(17): P(>=64) ~ 1e-19)
#define NEG_SLOPE 0.2f
#define PHASES  8
#define PRANGE  ((N_NODES + PHASES - 1) / PHASES)   // 6250
#define BPP     ((NE_TOT + 255) / 256)              // 3321 blocks per phase

typedef short v8s __attribute__((ext_vector_type(8)));
typedef float v4f __attribute__((ext_vector_type(4)));

// XOR swizzle: spreads stride-256B/128B row reads across 8 16B slots (T2)
#define SWZ(row, byte) ((byte) ^ (((row) & 7) << 4))

static __device__ __forceinline__ unsigned short f2bf(float f) {
    unsigned u = __float_as_uint(f);
    return (unsigned short)((u + 0x7FFF + ((u >> 16) & 1)) >> 16);  // RNE
}

// ---------------------------------------------------------------- utilities
__global__ void k_zero(int* __restrict__ cnt, float* __restrict__ sums) {
    int i = blockIdx.x * 256 + threadIdx.x;
    if (i < N_NODES) cnt[i] = 0;
    if (i < 128) sums[i] = 0.f;
}

// transpose + bf16-convert weights once: W1T[c][k] (64x128), W2T[c][k] (64x64)
__global__ void k_prep(const float* __restrict__ W1, const float* __restrict__ W2,
                       unsigned short* __restrict__ w1t, unsigned short* __restrict__ w2t) {
    int tid = threadIdx.x;
    for (int idx = tid; idx < 64 * IND; idx += 256) {
        int c = idx >> 7, k = idx & 127;
        w1t[idx] = f2bf(W1[k * 64 + c]);
    }
    for (int idx = tid; idx < 64 * 64; idx += 256) {
        int c = idx >> 6, k = idx & 63;
        w2t[idx] = f2bf(W2[k * 64 + c]);
    }
}

// ---------------------------------------------------------------- GEMM1 (MFMA bf16): h1 = x @ W1 + dots
// 64-row tile, 4 waves x 16 rows, 4 col-tiles, K=128 (4 mfma k-steps)
__global__ __launch_bounds__(256) void k_gemm1(
    const float* __restrict__ x, const unsigned short* __restrict__ w1t,
    const float* __restrict__ as_w, const float* __restrict__ ad_w,
    float* __restrict__ h, float* __restrict__ as_out, float* __restrict__ ad_out)
{
    __shared__ __align__(16) char sA[64 * 256];   // bf16 [row][k=128], swizzled
    __shared__ __align__(16) char sB[64 * 256];   // bf16 [col][k=128], swizzled
    __shared__ float sAs[64], sAd[64];
    int tid = threadIdx.x;
    int row0 = blockIdx.x * 64;

    // stage x tile: f32 -> bf16, coalesced reads  (rows = 256B = 32 x 8B chunks)
#pragma unroll
    for (int i = 0; i < 8; ++i) {                  // 2048 float4
        int idx = i * 256 + tid;
        int r = idx >> 5, c4 = idx & 31;
        int gr = row0 + r; if (gr >= N_NODES) gr = N_NODES - 1;
        float4 v = ((const float4*)(x + (size_t)gr * IND))[c4];
        ushort4 b; b.x = f2bf(v.x); b.y = f2bf(v.y); b.z = f2bf(v.z); b.w = f2bf(v.w);
        *(ushort4*)(sA + r * 256 + SWZ(r, c4 * 8)) = b;
    }
    // stage W1T into swizzled LDS  (rows = 256B = 16 x 16B chunks)
#pragma unroll
    for (int i = 0; i < 4; ++i) {                  // 1024 x 16B
        int idx = i * 256 + tid;
        int r = idx >> 4, c8 = idx & 15;           // FIXED: 16 chunks per row
        v8s wv = *(const v8s*)(w1t + idx * 8);
        *(v8s*)(sB + r * 256 + SWZ(r, c8 * 16)) = wv;
    }
    if (tid < 64) { sAs[tid] = as_w[tid]; sAd[tid] = ad_w[tid]; }
    __syncthreads();

    int w = tid >> 6, lane = tid & 63;
    int arow = w * 16 + (lane & 15);
    int kb   = (lane >> 4) * 16;                   // byte offset of this lane's 8-k slot
    v4f acc[4] = {};
#pragma unroll
    for (int ks = 0; ks < 4; ++ks) {
        v8s a = *(const v8s*)(sA + arow * 256 + SWZ(arow, ks * 64 + kb));
#pragma unroll
        for (int ct = 0; ct < 4; ++ct) {
            int brow = ct * 16 + (lane & 15);
            v8s b = *(const v8s*)(sB + brow * 256 + SWZ(brow, ks * 64 + kb));
            acc[ct] = __builtin_amdgcn_mfma_f32_16x16x32_bf16(a, b, acc[ct], 0, 0, 0);
        }
    }

    // epilogue: store h + attention dots.  C layout: col=lane&15, row=(lane>>4)*4+reg
    int cbase = lane & 15;
    int rloc  = (lane >> 4) * 4;
#pragma unroll
    for (int ct = 0; ct < 4; ++ct)
#pragma unroll
        for (int rg = 0; rg < 4; ++rg) {
            int row = row0 + w * 16 + rloc + rg;
            if (row < N_NODES) h[(size_t)row * 64 + ct * 16 + cbase] = acc[ct][rg];
        }
#pragma unroll
    for (int rg = 0; rg < 4; ++rg) {
        float vs = 0.f, vd = 0.f;
#pragma unroll
        for (int ct = 0; ct < 4; ++ct) {
            vs = fmaf(acc[ct][rg], sAs[ct * 16 + cbase], vs);
            vd = fmaf(acc[ct][rg], sAd[ct * 16 + cbase], vd);
        }
        vs += __shfl_xor(vs, 1, 64); vd += __shfl_xor(vd, 1, 64);
        vs += __shfl_xor(vs, 2, 64); vd += __shfl_xor(vd, 2, 64);
        vs += __shfl_xor(vs, 4, 64); vd += __shfl_xor(vd, 4, 64);
        vs += __shfl_xor(vs, 8, 64); vd += __shfl_xor(vd, 8, 64);
        int row = row0 + w * 16 + rloc + rg;
        if (cbase == 0 && row < N_NODES) { as_out[row] = vs; ad_out[row] = vd; }
    }
}

// ---------------------------------------------------------------- phase-partitioned edge scatter
// phase p commits only dst in [p*PRANGE,(p+1)*PRANGE): hot region L2-resident
__global__ void k_scatter(const int* __restrict__ ei, int* __restrict__ cnt,
                          unsigned short* __restrict__ bucket) {
    int phase = blockIdx.x / BPP;
    int e = (blockIdx.x % BPP) * 256 + threadIdx.x;
    if (e >= NE_TOT) return;
    int d = (e < E_EDGES) ? ei[E_EDGES + e] : (e - E_EDGES);
    int lo = phase * PRANGE;
    if (d < lo || d >= lo + PRANGE) return;
    int s = (e < E_EDGES) ? ei[e] : d;
    int pos = atomicAdd(&cnt[d], 1);
    if (pos < CAP) bucket[(size_t)pos * N_NODES + d] = (unsigned short)s;
}

// ---------------------------------------------------------------- per-dst softmax aggregation
__global__ __launch_bounds__(256) void k_agg(
    const float* __restrict__ hin, const float* __restrict__ as_, const float* __restrict__ ad_,
    const int* __restrict__ cnt, const unsigned short* __restrict__ bucket,
    const float* __restrict__ bias, float* __restrict__ out)
{
    int wave = threadIdx.x >> 6, lane = threadIdx.x & 63;
    int n = blockIdx.x * 4 + wave;
    if (n >= N_NODES) return;
    int deg = min(cnt[n], CAP);
    float adn = ad_[n];

    int s_l = 0;
    float e = -1e30f;
    if (lane < deg) {
        s_l = (int)bucket[(size_t)lane * N_NODES + n];
        float t = as_[s_l] + adn;
        e = t > 0.f ? t : NEG_SLOPE * t;
    }
    float m = e;
    for (int off = 32; off; off >>= 1) m = fmaxf(m, __shfl_xor(m, off, 64));
    float w_l = (lane < deg) ? __expf(e - m) : 0.f;
    float denom = w_l;
    for (int off = 32; off; off >>= 1) denom += __shfl_xor(denom, off, 64);

    float acc = 0.f;
    for (int t = 0; t < deg; t += 8) {
        int s0 = __shfl(s_l, t + 0), s1 = __shfl(s_l, t + 1);
        int s2 = __shfl(s_l, t + 2), s3 = __shfl(s_l, t + 3);
        int s4 = __shfl(s_l, t + 4), s5 = __shfl(s_l, t + 5);
        int s6 = __shfl(s_l, t + 6), s7 = __shfl(s_l, t + 7);
        float w0 = __shfl(w_l, t + 0), w1 = __shfl(w_l, t + 1);
        float w2 = __shfl(w_l, t + 2), w3 = __shfl(w_l, t + 3);
        float w4 = __shfl(w_l, t + 4), w5 = __shfl(w_l, t + 5);
        float w6 = __shfl(w_l, t + 6), w7 = __shfl(w_l, t + 7);
        float v0 = hin[(size_t)s0 * HID + lane];
        float v1 = hin[(size_t)s1 * HID + lane];
        float v2 = hin[(size_t)s2 * HID + lane];
        float v3 = hin[(size_t)s3 * HID + lane];
        float v4 = hin[(size_t)s4 * HID + lane];
        float v5 = hin[(size_t)s5 * HID + lane];
        float v6 = hin[(size_t)s6 * HID + lane];
        float v7 = hin[(size_t)s7 * HID + lane];
        acc = fmaf(w0, v0, acc); acc = fmaf(w1, v1, acc);
        acc = fmaf(w2, v2, acc); acc = fmaf(w3, v3, acc);
        acc = fmaf(w4, v4, acc); acc = fmaf(w5, v5, acc);
        acc = fmaf(w6, v6, acc); acc = fmaf(w7, v7, acc);
    }
    float inv = 1.f / (denom + 1e-16f);
    out[(size_t)n * HID + lane] = acc * inv + bias[lane];
}

// ---------------------------------------------------------------- BN statistics (two-stage)
__global__ __launch_bounds__(256) void k_bnstats(const float* __restrict__ h, float* __restrict__ sums) {
    int lane = threadIdx.x & 63, wave = threadIdx.x >> 6;
    float s = 0.f, ss = 0.f;
    for (int r = blockIdx.x * 4 + wave; r < N_NODES; r += gridDim.x * 4) {
        float v = h[(size_t)r * HID + lane];
        s += v; ss = fmaf(v, v, ss);
    }
    __shared__ float ls[4][64], lss[4][64];
    ls[wave][lane] = s; lss[wave][lane] = ss;
    __syncthreads();
    if (wave == 0) {
        s  = ls[0][lane] + ls[1][lane] + ls[2][lane] + ls[3][lane];
        ss = lss[0][lane] + lss[1][lane] + lss[2][lane] + lss[3][lane];
        atomicAdd(&sums[lane], s);
        atomicAdd(&sums[64 + lane], ss);
    }
}

__global__ void k_bnfinal(const float* __restrict__ sums, const float* __restrict__ gamma,
                          const float* __restrict__ beta, float* __restrict__ ss_out) {
    int j = threadIdx.x;
    if (j >= 64) return;
    float mean = sums[j] * (1.f / N_NODES);
    float var  = sums[64 + j] * (1.f / N_NODES) - mean * mean;
    float sc = gamma[j] * rsqrtf(var + 1e-5f);
    ss_out[j] = sc;
    ss_out[64 + j] = beta[j] - mean * sc;
}

// ---------------------------------------------------------------- GEMM2 (MFMA bf16), BN+ReLU fused
__global__ __launch_bounds__(256) void k_gemm2(
    const float* __restrict__ hin, const unsigned short* __restrict__ w2t,
    const float* __restrict__ ss,
    const float* __restrict__ as_w, const float* __restrict__ ad_w,
    float* __restrict__ h2, float* __restrict__ as_out, float* __restrict__ ad_out)
{
    __shared__ __align__(16) char sA[64 * 128];   // bf16 [row][k=64], swizzled
    __shared__ __align__(16) char sB[64 * 128];   // bf16 [col][k=64], swizzled
    __shared__ float sAs[64], sAd[64];
    int tid = threadIdx.x;
    int row0 = blockIdx.x * 64;

    // stage input tile with BN+ReLU, f32 -> bf16  (rows = 128B = 16 x 8B chunks)
#pragma unroll
    for (int i = 0; i < 4; ++i) {                  // 1024 float4
        int idx = i * 256 + tid;
        int r = idx >> 4, c4 = idx & 15;
        int gr = row0 + r; if (gr >= N_NODES) gr = N_NODES - 1;
        float4 v  = ((const float4*)(hin + (size_t)gr * 64))[c4];
        float4 sc = ((const float4*)ss)[c4];
        float4 sh = ((const float4*)(ss + 64))[c4];
        ushort4 b;
        b.x = f2bf(fmaxf(fmaf(v.x, sc.x, sh.x), 0.f));
        b.y = f2bf(fmaxf(fmaf(v.y, sc.y, sh.y), 0.f));
        b.z = f2bf(fmaxf(fmaf(v.z, sc.z, sh.z), 0.f));
        b.w = f2bf(fmaxf(fmaf(v.w, sc.w, sh.w), 0.f));
        *(ushort4*)(sA + r * 128 + SWZ(r, c4 * 8)) = b;
    }
    // stage W2T  (rows = 128B = 8 x 16B chunks)
#pragma unroll
    for (int i = 0; i < 2; ++i) {                  // 512 x 16B
        int idx = i * 256 + tid;
        int r = idx >> 3, c8 = idx & 7;            // FIXED: 8 chunks per row
        v8s wv = *(const v8s*)(w2t + idx * 8);
        *(v8s*)(sB + r * 128 + SWZ(r, c8 * 16)) = wv;
    }
    if (tid < 64) { sAs[tid] = as_w[tid]; sAd[tid] = ad_w[tid]; }
    __syncthreads();

    int w = tid >> 6, lane = tid & 63;
    int arow = w * 16 + (lane & 15);
    int kb   = (lane >> 4) * 16;
    v4f acc[4] = {};
#pragma unroll
    for (int ks = 0; ks < 2; ++ks) {
        v8s a = *(const v8s*)(sA + arow * 128 + SWZ(arow, ks * 64 + kb));
#pragma unroll
        for (int ct = 0; ct < 4; ++ct) {
            int brow = ct * 16 + (lane & 15);
            v8s b = *(const v8s*)(sB + brow * 128 + SWZ(brow, ks * 64 + kb));
            acc[ct] = __builtin_amdgcn_mfma_f32_16x16x32_bf16(a, b, acc[ct], 0, 0, 0);
        }
    }

    int cbase = lane & 15;
    int rloc  = (lane >> 4) * 4;
#pragma unroll
    for (int ct = 0; ct < 4; ++ct)
#pragma unroll
        for (int rg = 0; rg < 4; ++rg) {
            int row = row0 + w * 16 + rloc + rg;
            if (row < N_NODES) h2[(size_t)row * 64 + ct * 16 + cbase] = acc[ct][rg];
        }
#pragma unroll
    for (int rg = 0; rg < 4; ++rg) {
        float vs = 0.f, vd = 0.f;
#pragma unroll
        for (int ct = 0; ct < 4; ++ct) {
            vs = fmaf(acc[ct][rg], sAs[ct * 16 + cbase], vs);
            vd = fmaf(acc[ct][rg], sAd[ct * 16 + cbase], vd);
        }
        vs += __shfl_xor(vs, 1, 64); vd += __shfl_xor(vd, 1, 64);
        vs += __shfl_xor(vs, 2, 64); vd += __shfl_xor(vd, 2, 64);
        vs += __shfl_xor(vs, 4, 64); vd += __shfl_xor(vd, 4, 64);
        vs += __shfl_xor(vs, 8, 64); vd += __shfl_xor(vd, 8, 64);
        int row = row0 + w * 16 + rloc + rg;
        if (cbase == 0 && row < N_NODES) { as_out[row] = vs; ad_out[row] = vd; }
    }
}

// ---------------------------------------------------------------- launch
extern "C" void kernel_launch(void* const* d_in, const int* in_sizes, int n_in,
                              void* d_out, int out_size, void* d_ws, size_t ws_size,
                              hipStream_t stream) {
    const float* x        = (const float*)d_in[0];
    const int*   ei       = (const int*)d_in[1];
    const float* W1       = (const float*)d_in[2];
    const float* att_src1 = (const float*)d_in[3];
    const float* att_dst1 = (const float*)d_in[4];
    const float* bias1    = (const float*)d_in[5];
    const float* gamma    = (const float*)d_in[6];
    const float* beta     = (const float*)d_in[7];
    const float* W2       = (const float*)d_in[8];
    const float* att_src2 = (const float*)d_in[9];
    const float* att_dst2 = (const float*)d_in[10];
    const float* bias2    = (const float*)d_in[11];
    float* out = (float*)d_out;

    char* ws = (char*)d_ws;
    size_t off = 0;
    auto alloc = [&](size_t bytes) { void* p = ws + off; off = (off + bytes + 255) & ~(size_t)255; return p; };
    float* h1     = (float*)alloc((size_t)N_NODES * HID * 4);
    float* as1    = (float*)alloc((size_t)N_NODES * 4);
    float* ad1    = (float*)alloc((size_t)N_NODES * 4);
    float* h1agg  = (float*)alloc((size_t)N_NODES * HID * 4);
    float* h2     = (float*)alloc((size_t)N_NODES * HID * 4);
    float* as2    = (float*)alloc((size_t)N_NODES * 4);
    float* ad2    = (float*)alloc((size_t)N_NODES * 4);
    int*   cnt    = (int*)alloc((size_t)N_NODES * 4);
    unsigned short* bucket = (unsigned short*)alloc((size_t)CAP * N_NODES * 2);
    float* sums   = (float*)alloc(128 * 4);
    float* bn_ss  = (float*)alloc(128 * 4);
    unsigned short* w1t = (unsigned short*)alloc(64 * IND * 2);
    unsigned short* w2t = (unsigned short*)alloc(64 * 64 * 2);

    int gemmBlocks = (N_NODES + 63) / 64;   // 782
    k_zero<<<(N_NODES + 255) / 256, 256, 0, stream>>>(cnt, sums);
    k_prep<<<1, 256, 0, stream>>>(W1, W2, w1t, w2t);
    k_scatter<<<PHASES * BPP, 256, 0, stream>>>(ei, cnt, bucket);
    k_gemm1<<<gemmBlocks, 256, 0, stream>>>(x, w1t, att_src1, att_dst1, h1, as1, ad1);
    k_agg<<<(N_NODES + 3) / 4, 256, 0, stream>>>(h1, as1, ad1, cnt, bucket, bias1, h1agg);
    k_bnstats<<<256, 256, 0, stream>>>(h1agg, sums);
    k_bnfinal<<<1, 64, 0, stream>>>(sums, gamma, beta, bn_ss);
    k_gemm2<<<gemmBlocks, 256, 0, stream>>>(h1agg, w2t, bn_ss, att_src2, att_dst2, h2, as2, ad2);
    k_agg<<<(N_NODES + 3) / 4, 256, 0, stream>>>(h2, as2, ad2, cnt, bucket, bias2, out);
}

// Round 6
// 153.953 us; speedup vs baseline: 2.8249x; 1.0696x over previous
//
#include <hip/hip_runtime.h>

#define N_NODES 50000
#define E_EDGES 800000
#define NE_TOT  (E_EDGES + N_NODES)   // edges + self loops = 850000
#define IND     128
#define HID     64
#define CAP     64                    // max in-degree (Poisson(17): P(>=64) ~ 1e-19)
#define NEG_SLOPE 0.2f
#define PHASES  8
#define PRANGE  ((N_NODES + PHASES - 1) / PHASES)   // 6250
#define BPP     ((NE_TOT + 255) / 256)              // 3321 chunks

typedef short v8s __attribute__((ext_vector_type(8)));
typedef float v4f __attribute__((ext_vector_type(4)));

// XOR swizzle: spreads stride-256B/128B row reads across 8 16B slots (T2)
#define SWZ(row, byte) ((byte) ^ (((row) & 7) << 4))

static __device__ __forceinline__ unsigned short f2bf(float f) {
    unsigned u = __float_as_uint(f);
    return (unsigned short)((u + 0x7FFF + ((u >> 16) & 1)) >> 16);  // RNE
}
static __device__ __forceinline__ float bf2f(unsigned short u) {
    return __uint_as_float(((unsigned)u) << 16);
}

// ---------------------------------------------------------------- utilities
__global__ void k_zero(int* __restrict__ cnt, float* __restrict__ sums) {
    int i = blockIdx.x * 256 + threadIdx.x;
    if (i < N_NODES) cnt[i] = 0;
    if (i < 128) sums[i] = 0.f;
}

// transpose + bf16-convert weights once: W1T[c][k] (64x128), W2T[c][k] (64x64)
__global__ void k_prep(const float* __restrict__ W1, const float* __restrict__ W2,
                       unsigned short* __restrict__ w1t, unsigned short* __restrict__ w2t) {
    int tid = threadIdx.x;
    for (int idx = tid; idx < 64 * IND; idx += 256) {
        int c = idx >> 7, k = idx & 127;
        w1t[idx] = f2bf(W1[k * 64 + c]);
    }
    for (int idx = tid; idx < 64 * 64; idx += 256) {
        int c = idx >> 6, k = idx & 63;
        w2t[idx] = f2bf(W2[k * 64 + c]);
    }
}

// ---------------------------------------------------------------- GEMM1 (MFMA bf16): h1 = x @ W1 + dots
// h written as bf16 (gather payload for agg1)
__global__ __launch_bounds__(256) void k_gemm1(
    const float* __restrict__ x, const unsigned short* __restrict__ w1t,
    const float* __restrict__ as_w, const float* __restrict__ ad_w,
    unsigned short* __restrict__ hbf, float* __restrict__ as_out, float* __restrict__ ad_out)
{
    __shared__ __align__(16) char sA[64 * 256];   // bf16 [row][k=128], swizzled
    __shared__ __align__(16) char sB[64 * 256];   // bf16 [col][k=128], swizzled
    __shared__ float sAs[64], sAd[64];
    int tid = threadIdx.x;
    int row0 = blockIdx.x * 64;

    // stage x tile: f32 -> bf16, coalesced reads  (rows = 256B = 32 x 8B chunks)
#pragma unroll
    for (int i = 0; i < 8; ++i) {                  // 2048 float4
        int idx = i * 256 + tid;
        int r = idx >> 5, c4 = idx & 31;
        int gr = row0 + r; if (gr >= N_NODES) gr = N_NODES - 1;
        float4 v = ((const float4*)(x + (size_t)gr * IND))[c4];
        ushort4 b; b.x = f2bf(v.x); b.y = f2bf(v.y); b.z = f2bf(v.z); b.w = f2bf(v.w);
        *(ushort4*)(sA + r * 256 + SWZ(r, c4 * 8)) = b;
    }
    // stage W1T into swizzled LDS  (rows = 256B = 16 x 16B chunks)
#pragma unroll
    for (int i = 0; i < 4; ++i) {                  // 1024 x 16B
        int idx = i * 256 + tid;
        int r = idx >> 4, c8 = idx & 15;
        v8s wv = *(const v8s*)(w1t + idx * 8);
        *(v8s*)(sB + r * 256 + SWZ(r, c8 * 16)) = wv;
    }
    if (tid < 64) { sAs[tid] = as_w[tid]; sAd[tid] = ad_w[tid]; }
    __syncthreads();

    int w = tid >> 6, lane = tid & 63;
    int arow = w * 16 + (lane & 15);
    int kb   = (lane >> 4) * 16;
    v4f acc[4] = {};
#pragma unroll
    for (int ks = 0; ks < 4; ++ks) {
        v8s a = *(const v8s*)(sA + arow * 256 + SWZ(arow, ks * 64 + kb));
#pragma unroll
        for (int ct = 0; ct < 4; ++ct) {
            int brow = ct * 16 + (lane & 15);
            v8s b = *(const v8s*)(sB + brow * 256 + SWZ(brow, ks * 64 + kb));
            acc[ct] = __builtin_amdgcn_mfma_f32_16x16x32_bf16(a, b, acc[ct], 0, 0, 0);
        }
    }

    // epilogue: store h (bf16) + attention dots (f32)
    int cbase = lane & 15;
    int rloc  = (lane >> 4) * 4;
#pragma unroll
    for (int ct = 0; ct < 4; ++ct)
#pragma unroll
        for (int rg = 0; rg < 4; ++rg) {
            int row = row0 + w * 16 + rloc + rg;
            if (row < N_NODES) hbf[(size_t)row * 64 + ct * 16 + cbase] = f2bf(acc[ct][rg]);
        }
#pragma unroll
    for (int rg = 0; rg < 4; ++rg) {
        float vs = 0.f, vd = 0.f;
#pragma unroll
        for (int ct = 0; ct < 4; ++ct) {
            vs = fmaf(acc[ct][rg], sAs[ct * 16 + cbase], vs);
            vd = fmaf(acc[ct][rg], sAd[ct * 16 + cbase], vd);
        }
        vs += __shfl_xor(vs, 1, 64); vd += __shfl_xor(vd, 1, 64);
        vs += __shfl_xor(vs, 2, 64); vd += __shfl_xor(vd, 2, 64);
        vs += __shfl_xor(vs, 4, 64); vd += __shfl_xor(vd, 4, 64);
        vs += __shfl_xor(vs, 8, 64); vd += __shfl_xor(vd, 8, 64);
        int row = row0 + w * 16 + rloc + rg;
        if (cbase == 0 && row < N_NODES) { as_out[row] = vs; ad_out[row] = vd; }
    }
}

// ---------------------------------------------------------------- edge scatter, XCD-private phases
// phase = blockIdx & 7: with round-robin block->XCD mapping, each dst range is
// touched by exactly ONE XCD -> no cross-XCD line bouncing, single writeback.
__global__ void k_scatter(const int* __restrict__ ei, int* __restrict__ cnt,
                          unsigned short* __restrict__ bucket) {
    int phase = blockIdx.x & 7;
    int e = (blockIdx.x >> 3) * 256 + threadIdx.x;
    if (e >= NE_TOT) return;
    int d = (e < E_EDGES) ? ei[E_EDGES + e] : (e - E_EDGES);
    int lo = phase * PRANGE;
    if (d < lo || d >= lo + PRANGE) return;
    int s = (e < E_EDGES) ? ei[e] : d;
    int pos = atomicAdd(&cnt[d], 1);
    if (pos < CAP) bucket[(size_t)pos * N_NODES + d] = (unsigned short)s;
}

// ---------------------------------------------------------------- per-dst softmax aggregation
// h gathered as bf16 (128B per row), accumulate f32
__global__ __launch_bounds__(256) void k_agg(
    const unsigned short* __restrict__ hin, const float* __restrict__ as_, const float* __restrict__ ad_,
    const int* __restrict__ cnt, const unsigned short* __restrict__ bucket,
    const float* __restrict__ bias, float* __restrict__ out)
{
    int wave = threadIdx.x >> 6, lane = threadIdx.x & 63;
    int n = blockIdx.x * 4 + wave;
    if (n >= N_NODES) return;
    int deg = min(cnt[n], CAP);
    float adn = ad_[n];

    int s_l = 0;
    float e = -1e30f;
    if (lane < deg) {
        s_l = (int)bucket[(size_t)lane * N_NODES + n];
        float t = as_[s_l] + adn;
        e = t > 0.f ? t : NEG_SLOPE * t;
    }
    float m = e;
    for (int off = 32; off; off >>= 1) m = fmaxf(m, __shfl_xor(m, off, 64));
    float w_l = (lane < deg) ? __expf(e - m) : 0.f;
    float denom = w_l;
    for (int off = 32; off; off >>= 1) denom += __shfl_xor(denom, off, 64);

    float acc = 0.f;
    for (int t = 0; t < deg; t += 8) {
        int s0 = __shfl(s_l, t + 0), s1 = __shfl(s_l, t + 1);
        int s2 = __shfl(s_l, t + 2), s3 = __shfl(s_l, t + 3);
        int s4 = __shfl(s_l, t + 4), s5 = __shfl(s_l, t + 5);
        int s6 = __shfl(s_l, t + 6), s7 = __shfl(s_l, t + 7);
        float w0 = __shfl(w_l, t + 0), w1 = __shfl(w_l, t + 1);
        float w2 = __shfl(w_l, t + 2), w3 = __shfl(w_l, t + 3);
        float w4 = __shfl(w_l, t + 4), w5 = __shfl(w_l, t + 5);
        float w6 = __shfl(w_l, t + 6), w7 = __shfl(w_l, t + 7);
        float v0 = bf2f(hin[(size_t)s0 * HID + lane]);
        float v1 = bf2f(hin[(size_t)s1 * HID + lane]);
        float v2 = bf2f(hin[(size_t)s2 * HID + lane]);
        float v3 = bf2f(hin[(size_t)s3 * HID + lane]);
        float v4 = bf2f(hin[(size_t)s4 * HID + lane]);
        float v5 = bf2f(hin[(size_t)s5 * HID + lane]);
        float v6 = bf2f(hin[(size_t)s6 * HID + lane]);
        float v7 = bf2f(hin[(size_t)s7 * HID + lane]);
        acc = fmaf(w0, v0, acc); acc = fmaf(w1, v1, acc);
        acc = fmaf(w2, v2, acc); acc = fmaf(w3, v3, acc);
        acc = fmaf(w4, v4, acc); acc = fmaf(w5, v5, acc);
        acc = fmaf(w6, v6, acc); acc = fmaf(w7, v7, acc);
    }
    float inv = 1.f / (denom + 1e-16f);
    out[(size_t)n * HID + lane] = acc * inv + bias[lane];
}

// ---------------------------------------------------------------- BN statistics (two-stage)
__global__ __launch_bounds__(256) void k_bnstats(const float* __restrict__ h, float* __restrict__ sums) {
    int lane = threadIdx.x & 63, wave = threadIdx.x >> 6;
    float s = 0.f, ss = 0.f;
    for (int r = blockIdx.x * 4 + wave; r < N_NODES; r += gridDim.x * 4) {
        float v = h[(size_t)r * HID + lane];
        s += v; ss = fmaf(v, v, ss);
    }
    __shared__ float ls[4][64], lss[4][64];
    ls[wave][lane] = s; lss[wave][lane] = ss;
    __syncthreads();
    if (wave == 0) {
        s  = ls[0][lane] + ls[1][lane] + ls[2][lane] + ls[3][lane];
        ss = lss[0][lane] + lss[1][lane] + lss[2][lane] + lss[3][lane];
        atomicAdd(&sums[lane], s);
        atomicAdd(&sums[64 + lane], ss);
    }
}

__global__ void k_bnfinal(const float* __restrict__ sums, const float* __restrict__ gamma,
                          const float* __restrict__ beta, float* __restrict__ ss_out) {
    int j = threadIdx.x;
    if (j >= 64) return;
    float mean = sums[j] * (1.f / N_NODES);
    float var  = sums[64 + j] * (1.f / N_NODES) - mean * mean;
    float sc = gamma[j] * rsqrtf(var + 1e-5f);
    ss_out[j] = sc;
    ss_out[64 + j] = beta[j] - mean * sc;
}

// ---------------------------------------------------------------- GEMM2 (MFMA bf16), BN+ReLU fused
// h2 written as bf16 (gather payload for agg2)
__global__ __launch_bounds__(256) void k_gemm2(
    const float* __restrict__ hin, const unsigned short* __restrict__ w2t,
    const float* __restrict__ ss,
    const float* __restrict__ as_w, const float* __restrict__ ad_w,
    unsigned short* __restrict__ h2bf, float* __restrict__ as_out, float* __restrict__ ad_out)
{
    __shared__ __align__(16) char sA[64 * 128];   // bf16 [row][k=64], swizzled
    __shared__ __align__(16) char sB[64 * 128];   // bf16 [col][k=64], swizzled
    __shared__ float sAs[64], sAd[64];
    int tid = threadIdx.x;
    int row0 = blockIdx.x * 64;

    // stage input tile with BN+ReLU, f32 -> bf16  (rows = 128B = 16 x 8B chunks)
#pragma unroll
    for (int i = 0; i < 4; ++i) {                  // 1024 float4
        int idx = i * 256 + tid;
        int r = idx >> 4, c4 = idx & 15;
        int gr = row0 + r; if (gr >= N_NODES) gr = N_NODES - 1;
        float4 v  = ((const float4*)(hin + (size_t)gr * 64))[c4];
        float4 sc = ((const float4*)ss)[c4];
        float4 sh = ((const float4*)(ss + 64))[c4];
        ushort4 b;
        b.x = f2bf(fmaxf(fmaf(v.x, sc.x, sh.x), 0.f));
        b.y = f2bf(fmaxf(fmaf(v.y, sc.y, sh.y), 0.f));
        b.z = f2bf(fmaxf(fmaf(v.z, sc.z, sh.z), 0.f));
        b.w = f2bf(fmaxf(fmaf(v.w, sc.w, sh.w), 0.f));
        *(ushort4*)(sA + r * 128 + SWZ(r, c4 * 8)) = b;
    }
    // stage W2T  (rows = 128B = 8 x 16B chunks)
#pragma unroll
    for (int i = 0; i < 2; ++i) {                  // 512 x 16B
        int idx = i * 256 + tid;
        int r = idx >> 3, c8 = idx & 7;
        v8s wv = *(const v8s*)(w2t + idx * 8);
        *(v8s*)(sB + r * 128 + SWZ(r, c8 * 16)) = wv;
    }
    if (tid < 64) { sAs[tid] = as_w[tid]; sAd[tid] = ad_w[tid]; }
    __syncthreads();

    int w = tid >> 6, lane = tid & 63;
    int arow = w * 16 + (lane & 15);
    int kb   = (lane >> 4) * 16;
    v4f acc[4] = {};
#pragma unroll
    for (int ks = 0; ks < 2; ++ks) {
        v8s a = *(const v8s*)(sA + arow * 128 + SWZ(arow, ks * 64 + kb));
#pragma unroll
        for (int ct = 0; ct < 4; ++ct) {
            int brow = ct * 16 + (lane & 15);
            v8s b = *(const v8s*)(sB + brow * 128 + SWZ(brow, ks * 64 + kb));
            acc[ct] = __builtin_amdgcn_mfma_f32_16x16x32_bf16(a, b, acc[ct], 0, 0, 0);
        }
    }

    int cbase = lane & 15;
    int rloc  = (lane >> 4) * 4;
#pragma unroll
    for (int ct = 0; ct < 4; ++ct)
#pragma unroll
        for (int rg = 0; rg < 4; ++rg) {
            int row = row0 + w * 16 + rloc + rg;
            if (row < N_NODES) h2bf[(size_t)row * 64 + ct * 16 + cbase] = f2bf(acc[ct][rg]);
        }
#pragma unroll
    for (int rg = 0; rg < 4; ++rg) {
        float vs = 0.f, vd = 0.f;
#pragma unroll
        for (int ct = 0; ct < 4; ++ct) {
            vs = fmaf(acc[ct][rg], sAs[ct * 16 + cbase], vs);
            vd = fmaf(acc[ct][rg], sAd[ct * 16 + cbase], vd);
        }
        vs += __shfl_xor(vs, 1, 64); vd += __shfl_xor(vd, 1, 64);
        vs += __shfl_xor(vs, 2, 64); vd += __shfl_xor(vd, 2, 64);
        vs += __shfl_xor(vs, 4, 64); vd += __shfl_xor(vd, 4, 64);
        vs += __shfl_xor(vs, 8, 64); vd += __shfl_xor(vd, 8, 64);
        int row = row0 + w * 16 + rloc + rg;
        if (cbase == 0 && row < N_NODES) { as_out[row] = vs; ad_out[row] = vd; }
    }
}

// ---------------------------------------------------------------- launch
extern "C" void kernel_launch(void* const* d_in, const int* in_sizes, int n_in,
                              void* d_out, int out_size, void* d_ws, size_t ws_size,
                              hipStream_t stream) {
    const float* x        = (const float*)d_in[0];
    const int*   ei       = (const int*)d_in[1];
    const float* W1       = (const float*)d_in[2];
    const float* att_src1 = (const float*)d_in[3];
    const float* att_dst1 = (const float*)d_in[4];
    const float* bias1    = (const float*)d_in[5];
    const float* gamma    = (const float*)d_in[6];
    const float* beta     = (const float*)d_in[7];
    const float* W2       = (const float*)d_in[8];
    const float* att_src2 = (const float*)d_in[9];
    const float* att_dst2 = (const float*)d_in[10];
    const float* bias2    = (const float*)d_in[11];
    float* out = (float*)d_out;

    char* ws = (char*)d_ws;
    size_t off = 0;
    auto alloc = [&](size_t bytes) { void* p = ws + off; off = (off + bytes + 255) & ~(size_t)255; return p; };
    unsigned short* h1 = (unsigned short*)alloc((size_t)N_NODES * HID * 2);
    float* as1    = (float*)alloc((size_t)N_NODES * 4);
    float* ad1    = (float*)alloc((size_t)N_NODES * 4);
    float* h1agg  = (float*)alloc((size_t)N_NODES * HID * 4);
    unsigned short* h2 = (unsigned short*)alloc((size_t)N_NODES * HID * 2);
    float* as2    = (float*)alloc((size_t)N_NODES * 4);
    float* ad2    = (float*)alloc((size_t)N_NODES * 4);
    int*   cnt    = (int*)alloc((size_t)N_NODES * 4);
    unsigned short* bucket = (unsigned short*)alloc((size_t)CAP * N_NODES * 2);
    float* sums   = (float*)alloc(128 * 4);
    float* bn_ss  = (float*)alloc(128 * 4);
    unsigned short* w1t = (unsigned short*)alloc(64 * IND * 2);
    unsigned short* w2t = (unsigned short*)alloc(64 * 64 * 2);

    int gemmBlocks = (N_NODES + 63) / 64;   // 782
    k_zero<<<(N_NODES + 255) / 256, 256, 0, stream>>>(cnt, sums);
    k_prep<<<1, 256, 0, stream>>>(W1, W2, w1t, w2t);
    k_scatter<<<PHASES * BPP, 256, 0, stream>>>(ei, cnt, bucket);
    k_gemm1<<<gemmBlocks, 256, 0, stream>>>(x, w1t, att_src1, att_dst1, h1, as1, ad1);
    k_agg<<<(N_NODES + 3) / 4, 256, 0, stream>>>(h1, as1, ad1, cnt, bucket, bias1, h1agg);
    k_bnstats<<<256, 256, 0, stream>>>(h1agg, sums);
    k_bnfinal<<<1, 64, 0, stream>>>(sums, gamma, beta, bn_ss);
    k_gemm2<<<gemmBlocks, 256, 0, stream>>>(h1agg, w2t, bn_ss, att_src2, att_dst2, h2, as2, ad2);
    k_agg<<<(N_NODES + 3) / 4, 256, 0, stream>>>(h2, as2, ad2, cnt, bucket, bias2, out);
}